// Round 5
// baseline (144.543 us; speedup 1.0000x reference)
//
#include <hip/hip_runtime.h>

#define TPB 256
#define NBLK 1536      // 6 blocks/CU x 256 CU: matches launch_bounds(256,6) occupancy
#define REPL 8         // 8-way PAIR replication -> 256 entries * 8 copies * 8 B = 16 KB

__device__ __forceinline__ float fade_f(float t) {
    // 6t^5 - 15t^4 + 10t^3 (Horner, fmaf)
    return t * t * t * fmaf(t, fmaf(t, 6.0f, -15.0f), 10.0f);
}

__device__ __forceinline__ float lerp_f(float a, float b, float t) {
    return fmaf(t, b - a, a);
}

// Packed leaf word w: bits 0..5 = gi = perm[...] % 12, bits 6..13 = perm value <<6.
// grad3 rows: 0..3 = (±1,±1,0), 4..7 = (±1,0,±1), 8..11 = (0,±1,±1)
// c1 = gi<8 ? dx : dy ; c2 = gi<4 ? dy : dz ; signs = gi&1, gi&2.
__device__ __forceinline__ float gdot_w(unsigned w, float dx, float dy, float dz) {
    unsigned gi = w & 0x3Fu;
    float c1 = (gi < 8u) ? dx : dy;
    float c2 = (gi < 4u) ? dy : dz;
    unsigned s1 = w << 31;                    // bit0 -> sign of c1
    unsigned s2 = (w << 30) & 0x80000000u;    // bit1 -> sign of c2
    return __uint_as_float(__float_as_uint(c1) ^ s1)
         + __uint_as_float(__float_as_uint(c2) ^ s2);
}

// r4 post-mortem: VGPR stayed at 32 -> compiler SERIALIZED the element chains;
// the 3-level dependent LDS chain (~350+ cyc) ran fully exposed per element.
// This version stage-interleaves the 4 chains of one quad explicitly:
//   stage P: prologs + ALL level-1 reads issued
//   (fades as latency fill)
//   stage 2: ALL level-2 reads issued
//   stage 3: ALL level-3 reads issued
//   stage F: per-element gdot/lerp
// Every consumer sits after all 4 chains' issues of that level, so waits become
// partial lgkmcnt(N) instead of per-element drains. Costs ~70 live VGPRs ->
// launch_bounds(256,6) raises the cap to ~84 (24 waves/CU instead of 32).
__global__ __launch_bounds__(TPB, 6) void perlin_kernel(
    const float* __restrict__ xg, const float* __restrict__ yg,
    const float* __restrict__ zg, const int* __restrict__ perm,
    float* __restrict__ out, int nquads)
{
    // Packed PAIR table, 16 KB. T[i*8+c] = (W(perm[i]), W(perm[(i+1)&255])),
    // W(p) = (p<<6) | (p%12). One ds_read_b64 per (idx, idx+1) pair.
    // Entry byte stride = 64 B; (sum & 0x3FC0) wraps mod 256 entries and kills
    // packed low-bit garbage (garbage < 64, clean terms are multiples of 64).
    __shared__ uint2 T[256 * REPL];

    for (int s = threadIdx.x; s < 256 * REPL; s += TPB) {
        int i = s >> 3;  // REPL = 8
        unsigned p0 = (unsigned)perm[i];
        unsigned p1 = (unsigned)perm[(i + 1) & 255];
        T[s] = make_uint2((p0 << 6) | (p0 % 12u), (p1 << 6) | (p1 % 12u));
    }
    __syncthreads();

    const char* Tp = (const char*)T + ((threadIdx.x & (REPL - 1)) << 3);

    const float4* x4 = (const float4*)xg;
    const float4* y4 = (const float4*)yg;
    const float4* z4 = (const float4*)zg;
    float4* o4 = (float4*)out;

    const int stride = gridDim.x * TPB;
    for (int q = blockIdx.x * TPB + threadIdx.x; q < nquads; q += stride) {
        float4 xv = x4[q], yv = y4[q], zv = z4[q];

        // ---- stage P: prolog + level-1 issue, all 4 elements ----
        // coords in [0,64): floor == trunc; xi<<6 <= 4032 is in-bounds (no mask)
#define PROLOG(e, X, Y, Z)                                              \
        int xi##e = (int)(X), yi##e = (int)(Y), zi##e = (int)(Z);       \
        float xf##e = (X) - (float)xi##e;                               \
        float yf##e = (Y) - (float)yi##e;                               \
        float zf##e = (Z) - (float)zi##e;                               \
        unsigned y6##e = (unsigned)yi##e << 6;                          \
        unsigned z6##e = (unsigned)zi##e << 6;                          \
        uint2 AB##e = *(const uint2*)(Tp + ((unsigned)xi##e << 6));

        PROLOG(0, xv.x, yv.x, zv.x)
        PROLOG(1, xv.y, yv.y, zv.y)
        PROLOG(2, xv.z, yv.z, zv.z)
        PROLOG(3, xv.w, yv.w, zv.w)

        // ---- latency fill: fades are pure VALU on already-available fracs ----
        float u0 = fade_f(xf0), v0 = fade_f(yf0), w0 = fade_f(zf0);
        float u1 = fade_f(xf1), v1 = fade_f(yf1), w1 = fade_f(zf1);
        float u2 = fade_f(xf2), v2 = fade_f(yf2), w2 = fade_f(zf2);
        float u3 = fade_f(xf3), v3 = fade_f(yf3), w3 = fade_f(zf3);

        // ---- stage 2: level-2 issue, all 4 elements (8 ds_read_b64) ----
#define LVL2(e)                                                               \
        uint2 paa##e = *(const uint2*)(Tp + ((AB##e.x + y6##e) & 0x3FC0u));   \
        uint2 pba##e = *(const uint2*)(Tp + ((AB##e.y + y6##e) & 0x3FC0u));

        LVL2(0) LVL2(1) LVL2(2) LVL2(3)

        // ---- stage 3: level-3 issue, all 4 elements (16 ds_read_b64) ----
#define LVL3(e)                                                               \
        uint2 qaa##e = *(const uint2*)(Tp + ((paa##e.x + z6##e) & 0x3FC0u));  \
        uint2 qab##e = *(const uint2*)(Tp + ((paa##e.y + z6##e) & 0x3FC0u));  \
        uint2 qba##e = *(const uint2*)(Tp + ((pba##e.x + z6##e) & 0x3FC0u));  \
        uint2 qbb##e = *(const uint2*)(Tp + ((pba##e.y + z6##e) & 0x3FC0u));

        LVL3(0) LVL3(1) LVL3(2) LVL3(3)

        // ---- stage F: per-element finish (gdot + lerp tree) ----
#define FINISH(e, R)                                                          \
        {                                                                     \
        float xm = xf##e - 1.0f, ym = yf##e - 1.0f, zm = zf##e - 1.0f;        \
        float g_aaa = gdot_w(qaa##e.x, xf##e, yf##e, zf##e);                  \
        float g_aab = gdot_w(qaa##e.y, xf##e, yf##e, zm);                     \
        float g_aba = gdot_w(qab##e.x, xf##e, ym,    zf##e);                  \
        float g_abb = gdot_w(qab##e.y, xf##e, ym,    zm);                     \
        float g_baa = gdot_w(qba##e.x, xm,    yf##e, zf##e);                  \
        float g_bab = gdot_w(qba##e.y, xm,    yf##e, zm);                     \
        float g_bba = gdot_w(qbb##e.x, xm,    ym,    zf##e);                  \
        float g_bbb = gdot_w(qbb##e.y, xm,    ym,    zm);                     \
        float l1 = lerp_f(g_aaa, g_baa, u##e);                                \
        float l2 = lerp_f(g_aba, g_bba, u##e);                                \
        float l3 = lerp_f(g_aab, g_bab, u##e);                                \
        float l4 = lerp_f(g_abb, g_bbb, u##e);                                \
        float m1 = lerp_f(l1, l2, v##e);                                      \
        float m2 = lerp_f(l3, l4, v##e);                                      \
        R = lerp_f(m1, m2, w##e);                                             \
        }

        float r0, r1, r2, r3;
        FINISH(0, r0)
        FINISH(1, r1)
        FINISH(2, r2)
        FINISH(3, r3)

        o4[q] = make_float4(r0, r1, r2, r3);

#undef PROLOG
#undef LVL2
#undef LVL3
#undef FINISH
    }
}

extern "C" void kernel_launch(void* const* d_in, const int* in_sizes, int n_in,
                              void* d_out, int out_size, void* d_ws, size_t ws_size,
                              hipStream_t stream) {
    const float* x   = (const float*)d_in[0];
    const float* y   = (const float*)d_in[1];
    const float* z   = (const float*)d_in[2];
    const int* perm  = (const int*)d_in[3];
    // d_in[4] (grad3) unused: gradients derived arithmetically from the index
    float* out = (float*)d_out;
    int nquads = out_size >> 2;  // 32*512*512 divisible by 4
    perlin_kernel<<<NBLK, TPB, 0, stream>>>(x, y, z, perm, out, nquads);
}